// Round 9
// baseline (331.449 us; speedup 1.0000x reference)
//
#include <hip/hip_runtime.h>
#include <hip/hip_bf16.h>
#include <cstdint>
#include <cstddef>

// LocalMSA fused v11: v10 base (151us; exp2-fold + tree-sum kept) + two
// overlap changes:
//  A) Q^T projection moved AFTER __syncthreads (touches no LDS): pre-barrier
//     critical path 96->64 MFMA/wave; Q-proj MFMAs hide the prefetched c2=0
//     attention ds_reads issued right after the barrier.
//  B) attention c2 loop software-pipelined with TWO NAMED buffers (kA/vA,
//     kB/vB; static indexing per scratch rule) and fully unrolled: each
//     chunk's 8 ds_read_b128 issue a full compute-phase early; WAR deps on
//     the named buffers BOUND scheduler hoisting (v9b's spill came from 8
//     anonymous buffers). Pressure ~= v10's unroll-2 window.
// Arithmetic identical to v10 -> absmax must stay exactly 0.0078125.
// Sentinels: steady WRITE_SIZE <=149K KB (no spill), VGPR ~64 arch,
// LDS 65536, occupancy ~42%, bank conflict ~2.1M.

typedef __attribute__((ext_vector_type(8))) short v8s;
typedef __attribute__((ext_vector_type(4))) float v4f;
typedef __attribute__((ext_vector_type(4))) unsigned short v4u;
typedef __attribute__((ext_vector_type(4))) unsigned int v4i;

#define MFMA16(a, b, c) __builtin_amdgcn_mfma_f32_16x16x32_bf16((a), (b), (c), 0, 0, 0)

constexpr int LL = 256;
constexpr int CC = 128;
constexpr int CH = 64;
constexpr int KS_BYTES = 256 * 128;   // Ks [256 l][64 cc-slot] bf16, 128B rows
constexpr int VT_BYTES = 64 * 512;    // Vt [64 cc][256 l-slot] bf16, 512B rows

// 1/sqrt(128)*log2(e): Q pre-scale so QK^T lands in the log2 domain.
constexpr float QSCALE2 = 0.08838834764831845f * 1.4426950408889634f;

__device__ __forceinline__ unsigned short f2bf(float f) {
    union { __hip_bfloat16 b; unsigned short u; } cv;
    cv.b = __float2bfloat16(f);
    return cv.u;
}

// packed pair f32x2 -> bf16x2 (v_cvt_pk_bf16_f32; RNE == __float2bfloat16)
__device__ __forceinline__ unsigned int pk2(float lo, float hi) {
    union { __hip_bfloat162 b; unsigned int u; } cv;
    cv.b = __float22bfloat162_rn(float2{lo, hi});
    return cv.u;
}

__device__ __forceinline__ v8s load8_f32_bf16(const float* __restrict__ p) {
    float4 a = *reinterpret_cast<const float4*>(p);
    float4 b = *reinterpret_cast<const float4*>(p + 4);
    union { v4i i; v8s s; } u;
    u.i[0] = pk2(a.x, a.y);
    u.i[1] = pk2(a.z, a.w);
    u.i[2] = pk2(b.x, b.y);
    u.i[3] = pk2(b.z, b.w);
    return u.s;
}

__device__ __forceinline__ int swz128(int row, int byte_in_row) {
    return row * 128 + (byte_in_row ^ ((row & 7) << 4));
}
__device__ __forceinline__ int swz512(int row, int byte_in_row) {
    return row * 512 + (byte_in_row ^ ((row & 7) << 4));
}

// load one key-chunk's K/V fragments from LDS into named registers
__device__ __forceinline__ void ld_c2(const char* KsB, const char* VtB,
                                      int m_, int g, int c2,
                                      v8s (&kf0)[2], v8s (&kf1)[2], v8s (&vf)[4])
{
    #pragma unroll
    for (int ks = 0; ks < 2; ++ks)
        kf0[ks] = *reinterpret_cast<const v8s*>(
            KsB + swz128(32 * c2 + m_, (32 * ks + 8 * g) << 1));
    #pragma unroll
    for (int ks = 0; ks < 2; ++ks)
        kf1[ks] = *reinterpret_cast<const v8s*>(
            KsB + swz128(32 * c2 + 16 + m_, (32 * ks + 8 * g) << 1));
    #pragma unroll
    for (int nt = 0; nt < 4; ++nt)
        vf[nt] = *reinterpret_cast<const v8s*>(
            VtB + swz512(16 * nt + m_, 64 * c2 + 16 * g));
}

// one key-chunk of attention: QK^T (2 chains), exp2, pack, PV accumulate
__device__ __forceinline__ void att_c2(const v8s (&kf0)[2], const v8s (&kf1)[2],
                                       const v8s (&vf)[4], const v8s (&qf)[2][2],
                                       v4f (&o)[2][4], float (&sm)[2])
{
    #pragma unroll
    for (int chk = 0; chk < 2; ++chk) {
        v4f s0 = {0.f, 0.f, 0.f, 0.f}, s1 = {0.f, 0.f, 0.f, 0.f};
        #pragma unroll
        for (int ks = 0; ks < 2; ++ks) s0 = MFMA16(kf0[ks], qf[chk][ks], s0);
        #pragma unroll
        for (int ks = 0; ks < 2; ++ks) s1 = MFMA16(kf1[ks], qf[chk][ks], s1);

        // lane(m_,g): P[q=m_][k=32c2+16t+4g+r]; A-frag slot 8g+j: t=j>>2, r=j&3
        // S is in the log2 domain (Q pre-scaled by log2e): v_exp_f32 direct.
        const float p0 = __builtin_amdgcn_exp2f(s0[0]);
        const float p1 = __builtin_amdgcn_exp2f(s0[1]);
        const float p2 = __builtin_amdgcn_exp2f(s0[2]);
        const float p3 = __builtin_amdgcn_exp2f(s0[3]);
        const float p4 = __builtin_amdgcn_exp2f(s1[0]);
        const float p5 = __builtin_amdgcn_exp2f(s1[1]);
        const float p6 = __builtin_amdgcn_exp2f(s1[2]);
        const float p7 = __builtin_amdgcn_exp2f(s1[3]);
        sm[chk] += ((p0 + p1) + (p2 + p3)) + ((p4 + p5) + (p6 + p7));
        union { v4i i4; v8s s8; } up;
        up.i4[0] = pk2(p0, p1);
        up.i4[1] = pk2(p2, p3);
        up.i4[2] = pk2(p4, p5);
        up.i4[3] = pk2(p6, p7);
        const v8s pf = up.s8;

        __builtin_amdgcn_s_setprio(1);
        #pragma unroll
        for (int nt = 0; nt < 4; ++nt)
            o[chk][nt] = MFMA16(pf, vf[nt], o[chk][nt]);
        __builtin_amdgcn_s_setprio(0);
    }
}

// W fp32 -> bf16; Q rows (0..127) pre-scaled by 1/sqrt(128)*log2(e)
__global__ __launch_bounds__(256) void wconv_kernel(
    const float* __restrict__ W, unsigned short* __restrict__ Wb)
{
    int i = blockIdx.x * 256 + threadIdx.x;
    float4 v = reinterpret_cast<const float4*>(W)[i];
    const float s = (i < 4096) ? QSCALE2 : 1.0f;
    v4u o;
    o[0] = f2bf(v.x * s); o[1] = f2bf(v.y * s); o[2] = f2bf(v.z * s); o[3] = f2bf(v.w * s);
    reinterpret_cast<v4u*>(Wb)[i] = o;
}

__global__ __launch_bounds__(512, 4) void lmsa_kernel(
    const float* __restrict__ x, const unsigned short* __restrict__ Wb,
    const float* __restrict__ bias, float* __restrict__ out)
{
    __shared__ char smem[KS_BYTES + VT_BYTES];   // 64 KB static
    char* KsB = smem;
    char* VtB = smem + KS_BYTES;

    const int bgh  = blockIdx.x;
    const int bg   = bgh >> 1;
    const int h    = bgh & 1;
    const int tid  = threadIdx.x;
    const int wave = tid >> 6;
    const int lane = tid & 63;
    const int m_   = lane & 15;
    const int g    = lane >> 4;
    const int pm   = 8 * (m_ >> 2) + (m_ & 3);   // within-32 slot base

    const float* xB = x + (size_t)bg * (LL * CC);
    const size_t obase0 = (size_t)bg * (LL * CC);

    const unsigned short* Wq = Wb + (0 * CC + h * CH) * CC;   // pre-scaled (incl log2e)
    const unsigned short* Wk = Wb + (1 * CC + h * CH) * CC;
    const unsigned short* Wv = Wb + (2 * CC + h * CH) * CC;
    const float* bq = bias + 0 * CC + h * CH;
    const float* bk = bias + 1 * CC + h * CH;
    const float* bv = bias + 2 * CC + h * CH;

    // K bias hoist (indexed by col = 16nt+m_)
    float bkr[4];
    #pragma unroll
    for (int nt = 0; nt < 4; ++nt) bkr[nt] = bk[16 * nt + m_];

    // x fragments for this wave's rows [32w, 32w+32)
    v8s af[2][4];
    #pragma unroll
    for (int i = 0; i < 2; ++i)
        #pragma unroll
        for (int ks = 0; ks < 4; ++ks)
            af[i][ks] = load8_f32_bf16(xB + (32 * wave + 16 * i + m_) * CC + 32 * ks + 8 * g);

    // ---- K section: D[l][cc]; row=l=16(2w+i)+4g+r, phys cc=16nt+m_ -> permuted ----
    #pragma unroll 2
    for (int nt = 0; nt < 4; ++nt) {
        v8s bf[4];
        #pragma unroll
        for (int ks = 0; ks < 4; ++ks)
            bf[ks] = *reinterpret_cast<const v8s*>(Wk + (16 * nt + m_) * CC + 32 * ks + 8 * g);
        const int kcol = (32 * (nt >> 1) + 4 * (nt & 1) + pm) << 1;
        #pragma unroll
        for (int i = 0; i < 2; ++i) {
            v4f acc = {0.f, 0.f, 0.f, 0.f};
            #pragma unroll
            for (int ks = 0; ks < 4; ++ks) acc = MFMA16(af[i][ks], bf[ks], acc);
            const int row0 = 16 * (2 * wave + i) + 4 * g;
            const unsigned int d0 = pk2(acc[0] + bkr[nt], acc[1] + bkr[nt]);
            const unsigned int d1 = pk2(acc[2] + bkr[nt], acc[3] + bkr[nt]);
            *(unsigned short*)(KsB + swz128(row0 + 0, kcol)) = (unsigned short)d0;
            *(unsigned short*)(KsB + swz128(row0 + 1, kcol)) = (unsigned short)(d0 >> 16);
            *(unsigned short*)(KsB + swz128(row0 + 2, kcol)) = (unsigned short)d1;
            *(unsigned short*)(KsB + swz128(row0 + 3, kcol)) = (unsigned short)(d1 >> 16);
        }
    }

    // ---- Vt section: D[cc][l]; row=cc=16mtc+4g+r, phys l=16(2w+i)+m_ -> permuted ----
    #pragma unroll 2
    for (int mtc = 0; mtc < 4; ++mtc) {
        v8s wf[4];
        #pragma unroll
        for (int ks = 0; ks < 4; ++ks)
            wf[ks] = *reinterpret_cast<const v8s*>(Wv + (16 * mtc + m_) * CC + 32 * ks + 8 * g);
        v4f bvv = *reinterpret_cast<const v4f*>(bv + 16 * mtc + 4 * g);
        #pragma unroll
        for (int i = 0; i < 2; ++i) {
            const int mt = 2 * wave + i;
            const int vcol = (32 * (mt >> 1) + 4 * (mt & 1) + pm) << 1;
            v4f acc = {0.f, 0.f, 0.f, 0.f};
            #pragma unroll
            for (int ks = 0; ks < 4; ++ks) acc = MFMA16(wf[ks], af[i][ks], acc);
            const int row0 = 16 * mtc + 4 * g;
            const unsigned int d0 = pk2(acc[0] + bvv[0], acc[1] + bvv[1]);
            const unsigned int d1 = pk2(acc[2] + bvv[2], acc[3] + bvv[3]);
            *(unsigned short*)(VtB + swz512(row0 + 0, vcol)) = (unsigned short)d0;
            *(unsigned short*)(VtB + swz512(row0 + 1, vcol)) = (unsigned short)(d0 >> 16);
            *(unsigned short*)(VtB + swz512(row0 + 2, vcol)) = (unsigned short)d1;
            *(unsigned short*)(VtB + swz512(row0 + 3, vcol)) = (unsigned short)(d1 >> 16);
        }
    }

    __syncthreads();

    // ---- prefetch c2=0 attention fragments (hidden under Q-proj below) ----
    v8s kA0[2], kA1[2], vA[4], kB0[2], kB1[2], vB[4];
    ld_c2(KsB, VtB, m_, g, 0, kA0, kA1, vA);

    // ---- Q^T section (no LDS access -> legal after barrier) ----
    v8s qf[2][2];
    #pragma unroll
    for (int i = 0; i < 2; ++i) {
        v4f qacc[4];
        #pragma unroll
        for (int mtc = 0; mtc < 4; ++mtc) {
            v4f acc = {0.f, 0.f, 0.f, 0.f};
            #pragma unroll
            for (int ks = 0; ks < 4; ++ks) {
                v8s wf = *reinterpret_cast<const v8s*>(Wq + (16 * mtc + m_) * CC + 32 * ks + 8 * g);
                acc = MFMA16(wf, af[i][ks], acc);
            }
            #pragma unroll
            for (int r = 0; r < 4; ++r)
                qacc[mtc][r] = acc[r] + bq[16 * mtc + 4 * g + r] * QSCALE2;  // Wq pre-scaled
        }
        // pack B-frag: slot 8g+j <-> phys cc 32ks+16(j>>2)+4g+(j&3)
        #pragma unroll
        for (int ks = 0; ks < 2; ++ks) {
            union { v4i i4; v8s s8; } u;
            u.i4[0] = pk2(qacc[2 * ks][0],     qacc[2 * ks][1]);
            u.i4[1] = pk2(qacc[2 * ks][2],     qacc[2 * ks][3]);
            u.i4[2] = pk2(qacc[2 * ks + 1][0], qacc[2 * ks + 1][1]);
            u.i4[3] = pk2(qacc[2 * ks + 1][2], qacc[2 * ks + 1][3]);
            qf[i][ks] = u.s8;
        }
    }

    // ------- attention: explicit 2-buffer software pipeline over 8 chunks ----
    v4f o[2][4];
    #pragma unroll
    for (int chk = 0; chk < 2; ++chk)
        #pragma unroll
        for (int nt = 0; nt < 4; ++nt) o[chk][nt] = v4f{0.f, 0.f, 0.f, 0.f};
    float sm[2] = {0.f, 0.f};

    #pragma unroll
    for (int c2o = 0; c2o < 4; ++c2o) {
        ld_c2(KsB, VtB, m_, g, 2 * c2o + 1, kB0, kB1, vB);   // next chunk loads
        att_c2(kA0, kA1, vA, qf, o, sm);                     // compute current
        if (c2o != 3)
            ld_c2(KsB, VtB, m_, g, 2 * c2o + 2, kA0, kA1, vA);
        att_c2(kB0, kB1, vB, qf, o, sm);
    }

    // ------- normalize + store: q rows = 32*wave + 16*chk + 4g + r -------
    #pragma unroll
    for (int chk = 0; chk < 2; ++chk) {
        float s = sm[chk];
        s += __shfl_xor(s, 16, 64);
        s += __shfl_xor(s, 32, 64);
        float inv[4];
        #pragma unroll
        for (int r = 0; r < 4; ++r) inv[r] = 1.0f / __shfl(s, 4 * g + r, 64);

        const int rowb = 32 * wave + 16 * chk;
        #pragma unroll
        for (int nt = 0; nt < 4; ++nt)
            #pragma unroll
            for (int r = 0; r < 4; ++r)
                out[obase0 + (size_t)(rowb + 4 * g + r) * CC + h * CH + 16 * nt + m_] =
                    o[chk][nt][r] * inv[r];
    }
}

extern "C" void kernel_launch(void* const* d_in, const int* in_sizes, int n_in,
                              void* d_out, int out_size, void* d_ws, size_t ws_size,
                              hipStream_t stream) {
    (void)in_sizes; (void)n_in; (void)ws_size; (void)out_size;
    const float* x = (const float*)d_in[0];
    const float* W = (const float*)d_in[1];
    const float* b = (const float*)d_in[2];
    float* out = (float*)d_out;
    unsigned short* Wb = (unsigned short*)d_ws;   // 96 KB bf16 W (Q rows pre-scaled)

    wconv_kernel<<<dim3(48), dim3(256), 0, stream>>>(W, Wb);
    lmsa_kernel<<<dim3(2048), dim3(512), 0, stream>>>(x, Wb, b, out);
}

// Round 10
// 154.834 us; speedup vs baseline: 2.1407x; 2.1407x over previous
//
#include <hip/hip_runtime.h>
#include <hip/hip_bf16.h>
#include <cstdint>
#include <cstddef>

// LocalMSA fused v12: v10 base (151.2us known-good) + two zero-register-cost
// changes, isolated from v11's spill-causing pipeline:
//  a) s_setprio REMOVED from the PV cluster: T5 only pays with phase-diverse
//     waves (m190: hurts lockstep); our 8 waves run near-lockstep after one
//     shared barrier -> suspected standing tax carried since v3, never ablated.
//  b) Q^T projection moved AFTER __syncthreads (no LDS access), WITHOUT any
//     prefetch or explicit pipeline (v11's spill source): pre-barrier path
//     drops 96->64 MFMA/wave; post-barrier, Q-proj W-loads (L2 ~200cy)
//     overlap the attention loop's qf-independent first ds_reads. The loop
//     head remains a natural scheduling fence -> compiler throttles hoisting
//     instead of spilling (v9b/v11 lesson: forced order => spill).
// Arithmetic identical to v10 -> absmax must stay exactly 0.0078125.
// Sentinels: steady WRITE_SIZE ~148K KB (no spill; jump => revert b),
// VGPR 64 arch, LDS 65536, occupancy ~42%, bank conflict ~2.1M.

typedef __attribute__((ext_vector_type(8))) short v8s;
typedef __attribute__((ext_vector_type(4))) float v4f;
typedef __attribute__((ext_vector_type(4))) unsigned short v4u;
typedef __attribute__((ext_vector_type(4))) unsigned int v4i;

#define MFMA16(a, b, c) __builtin_amdgcn_mfma_f32_16x16x32_bf16((a), (b), (c), 0, 0, 0)

constexpr int LL = 256;
constexpr int CC = 128;
constexpr int CH = 64;
constexpr int KS_BYTES = 256 * 128;   // Ks [256 l][64 cc-slot] bf16, 128B rows
constexpr int VT_BYTES = 64 * 512;    // Vt [64 cc][256 l-slot] bf16, 512B rows

// 1/sqrt(128)*log2(e): Q pre-scale so QK^T lands in the log2 domain.
constexpr float QSCALE2 = 0.08838834764831845f * 1.4426950408889634f;

__device__ __forceinline__ unsigned short f2bf(float f) {
    union { __hip_bfloat16 b; unsigned short u; } cv;
    cv.b = __float2bfloat16(f);
    return cv.u;
}

// packed pair f32x2 -> bf16x2 (v_cvt_pk_bf16_f32; RNE == __float2bfloat16)
__device__ __forceinline__ unsigned int pk2(float lo, float hi) {
    union { __hip_bfloat162 b; unsigned int u; } cv;
    cv.b = __float22bfloat162_rn(float2{lo, hi});
    return cv.u;
}

__device__ __forceinline__ v8s load8_f32_bf16(const float* __restrict__ p) {
    float4 a = *reinterpret_cast<const float4*>(p);
    float4 b = *reinterpret_cast<const float4*>(p + 4);
    union { v4i i; v8s s; } u;
    u.i[0] = pk2(a.x, a.y);
    u.i[1] = pk2(a.z, a.w);
    u.i[2] = pk2(b.x, b.y);
    u.i[3] = pk2(b.z, b.w);
    return u.s;
}

__device__ __forceinline__ int swz128(int row, int byte_in_row) {
    return row * 128 + (byte_in_row ^ ((row & 7) << 4));
}
__device__ __forceinline__ int swz512(int row, int byte_in_row) {
    return row * 512 + (byte_in_row ^ ((row & 7) << 4));
}

// W fp32 -> bf16; Q rows (0..127) pre-scaled by 1/sqrt(128)*log2(e)
__global__ __launch_bounds__(256) void wconv_kernel(
    const float* __restrict__ W, unsigned short* __restrict__ Wb)
{
    int i = blockIdx.x * 256 + threadIdx.x;
    float4 v = reinterpret_cast<const float4*>(W)[i];
    const float s = (i < 4096) ? QSCALE2 : 1.0f;
    v4u o;
    o[0] = f2bf(v.x * s); o[1] = f2bf(v.y * s); o[2] = f2bf(v.z * s); o[3] = f2bf(v.w * s);
    reinterpret_cast<v4u*>(Wb)[i] = o;
}

__global__ __launch_bounds__(512, 4) void lmsa_kernel(
    const float* __restrict__ x, const unsigned short* __restrict__ Wb,
    const float* __restrict__ bias, float* __restrict__ out)
{
    __shared__ char smem[KS_BYTES + VT_BYTES];   // 64 KB static
    char* KsB = smem;
    char* VtB = smem + KS_BYTES;

    const int bgh  = blockIdx.x;
    const int bg   = bgh >> 1;
    const int h    = bgh & 1;
    const int tid  = threadIdx.x;
    const int wave = tid >> 6;
    const int lane = tid & 63;
    const int m_   = lane & 15;
    const int g    = lane >> 4;
    const int pm   = 8 * (m_ >> 2) + (m_ & 3);   // within-32 slot base

    const float* xB = x + (size_t)bg * (LL * CC);
    const size_t obase0 = (size_t)bg * (LL * CC);

    const unsigned short* Wq = Wb + (0 * CC + h * CH) * CC;   // pre-scaled (incl log2e)
    const unsigned short* Wk = Wb + (1 * CC + h * CH) * CC;
    const unsigned short* Wv = Wb + (2 * CC + h * CH) * CC;
    const float* bq = bias + 0 * CC + h * CH;
    const float* bk = bias + 1 * CC + h * CH;
    const float* bv = bias + 2 * CC + h * CH;

    // K bias hoist (indexed by col = 16nt+m_)
    float bkr[4];
    #pragma unroll
    for (int nt = 0; nt < 4; ++nt) bkr[nt] = bk[16 * nt + m_];

    // x fragments for this wave's rows [32w, 32w+32)
    v8s af[2][4];
    #pragma unroll
    for (int i = 0; i < 2; ++i)
        #pragma unroll
        for (int ks = 0; ks < 4; ++ks)
            af[i][ks] = load8_f32_bf16(xB + (32 * wave + 16 * i + m_) * CC + 32 * ks + 8 * g);

    // ---- K section: D[l][cc]; row=l=16(2w+i)+4g+r, phys cc=16nt+m_ -> permuted ----
    #pragma unroll 2
    for (int nt = 0; nt < 4; ++nt) {
        v8s bf[4];
        #pragma unroll
        for (int ks = 0; ks < 4; ++ks)
            bf[ks] = *reinterpret_cast<const v8s*>(Wk + (16 * nt + m_) * CC + 32 * ks + 8 * g);
        const int kcol = (32 * (nt >> 1) + 4 * (nt & 1) + pm) << 1;
        #pragma unroll
        for (int i = 0; i < 2; ++i) {
            v4f acc = {0.f, 0.f, 0.f, 0.f};
            #pragma unroll
            for (int ks = 0; ks < 4; ++ks) acc = MFMA16(af[i][ks], bf[ks], acc);
            const int row0 = 16 * (2 * wave + i) + 4 * g;
            const unsigned int d0 = pk2(acc[0] + bkr[nt], acc[1] + bkr[nt]);
            const unsigned int d1 = pk2(acc[2] + bkr[nt], acc[3] + bkr[nt]);
            *(unsigned short*)(KsB + swz128(row0 + 0, kcol)) = (unsigned short)d0;
            *(unsigned short*)(KsB + swz128(row0 + 1, kcol)) = (unsigned short)(d0 >> 16);
            *(unsigned short*)(KsB + swz128(row0 + 2, kcol)) = (unsigned short)d1;
            *(unsigned short*)(KsB + swz128(row0 + 3, kcol)) = (unsigned short)(d1 >> 16);
        }
    }

    // ---- Vt section: D[cc][l]; row=cc=16mtc+4g+r, phys l=16(2w+i)+m_ -> permuted ----
    #pragma unroll 2
    for (int mtc = 0; mtc < 4; ++mtc) {
        v8s wf[4];
        #pragma unroll
        for (int ks = 0; ks < 4; ++ks)
            wf[ks] = *reinterpret_cast<const v8s*>(Wv + (16 * mtc + m_) * CC + 32 * ks + 8 * g);
        v4f bvv = *reinterpret_cast<const v4f*>(bv + 16 * mtc + 4 * g);
        #pragma unroll
        for (int i = 0; i < 2; ++i) {
            const int mt = 2 * wave + i;
            const int vcol = (32 * (mt >> 1) + 4 * (mt & 1) + pm) << 1;
            v4f acc = {0.f, 0.f, 0.f, 0.f};
            #pragma unroll
            for (int ks = 0; ks < 4; ++ks) acc = MFMA16(wf[ks], af[i][ks], acc);
            const int row0 = 16 * mtc + 4 * g;
            const unsigned int d0 = pk2(acc[0] + bvv[0], acc[1] + bvv[1]);
            const unsigned int d1 = pk2(acc[2] + bvv[2], acc[3] + bvv[3]);
            *(unsigned short*)(VtB + swz512(row0 + 0, vcol)) = (unsigned short)d0;
            *(unsigned short*)(VtB + swz512(row0 + 1, vcol)) = (unsigned short)(d0 >> 16);
            *(unsigned short*)(VtB + swz512(row0 + 2, vcol)) = (unsigned short)d1;
            *(unsigned short*)(VtB + swz512(row0 + 3, vcol)) = (unsigned short)(d1 >> 16);
        }
    }

    __syncthreads();

    // ---- Q^T section (no LDS access -> moved after barrier; W-loads overlap
    //      the attention loop's qf-independent first ds_reads) ----
    v8s qf[2][2];
    #pragma unroll
    for (int i = 0; i < 2; ++i) {
        v4f qacc[4];
        #pragma unroll
        for (int mtc = 0; mtc < 4; ++mtc) {
            v4f acc = {0.f, 0.f, 0.f, 0.f};
            #pragma unroll
            for (int ks = 0; ks < 4; ++ks) {
                v8s wf = *reinterpret_cast<const v8s*>(Wq + (16 * mtc + m_) * CC + 32 * ks + 8 * g);
                acc = MFMA16(wf, af[i][ks], acc);
            }
            #pragma unroll
            for (int r = 0; r < 4; ++r)
                qacc[mtc][r] = acc[r] + bq[16 * mtc + 4 * g + r] * QSCALE2;  // Wq pre-scaled
        }
        // pack B-frag: slot 8g+j <-> phys cc 32ks+16(j>>2)+4g+(j&3)
        #pragma unroll
        for (int ks = 0; ks < 2; ++ks) {
            union { v4i i4; v8s s8; } u;
            u.i4[0] = pk2(qacc[2 * ks][0],     qacc[2 * ks][1]);
            u.i4[1] = pk2(qacc[2 * ks][2],     qacc[2 * ks][3]);
            u.i4[2] = pk2(qacc[2 * ks + 1][0], qacc[2 * ks + 1][1]);
            u.i4[3] = pk2(qacc[2 * ks + 1][2], qacc[2 * ks + 1][3]);
            qf[i][ks] = u.s8;
        }
    }

    // ------- attention: c2 outer (shared kf/vf reads), chk inner (2 chains) ---
    v4f o[2][4];
    #pragma unroll
    for (int chk = 0; chk < 2; ++chk)
        #pragma unroll
        for (int nt = 0; nt < 4; ++nt) o[chk][nt] = v4f{0.f, 0.f, 0.f, 0.f};
    float sm[2] = {0.f, 0.f};

    #pragma unroll 2
    for (int c2 = 0; c2 < 8; ++c2) {       // 8 key-chunks of 32
        // shared LDS reads for this chunk (used by BOTH chk chains)
        v8s kf0[2], kf1[2], vf[4];
        #pragma unroll
        for (int ks = 0; ks < 2; ++ks)
            kf0[ks] = *reinterpret_cast<const v8s*>(
                KsB + swz128(32 * c2 + m_, (32 * ks + 8 * g) << 1));
        #pragma unroll
        for (int ks = 0; ks < 2; ++ks)
            kf1[ks] = *reinterpret_cast<const v8s*>(
                KsB + swz128(32 * c2 + 16 + m_, (32 * ks + 8 * g) << 1));
        #pragma unroll
        for (int nt = 0; nt < 4; ++nt)
            vf[nt] = *reinterpret_cast<const v8s*>(
                VtB + swz512(16 * nt + m_, 64 * c2 + 16 * g));

        #pragma unroll
        for (int chk = 0; chk < 2; ++chk) {
            v4f s0 = {0.f, 0.f, 0.f, 0.f}, s1 = {0.f, 0.f, 0.f, 0.f};
            #pragma unroll
            for (int ks = 0; ks < 2; ++ks) s0 = MFMA16(kf0[ks], qf[chk][ks], s0);
            #pragma unroll
            for (int ks = 0; ks < 2; ++ks) s1 = MFMA16(kf1[ks], qf[chk][ks], s1);

            // lane(m_,g): P[q=m_][k=32c2+16t+4g+r]; A-frag slot 8g+j: t=j>>2, r=j&3
            // S is in the log2 domain (Q pre-scaled by log2e): v_exp_f32 direct.
            const float p0 = __builtin_amdgcn_exp2f(s0[0]);
            const float p1 = __builtin_amdgcn_exp2f(s0[1]);
            const float p2 = __builtin_amdgcn_exp2f(s0[2]);
            const float p3 = __builtin_amdgcn_exp2f(s0[3]);
            const float p4 = __builtin_amdgcn_exp2f(s1[0]);
            const float p5 = __builtin_amdgcn_exp2f(s1[1]);
            const float p6 = __builtin_amdgcn_exp2f(s1[2]);
            const float p7 = __builtin_amdgcn_exp2f(s1[3]);
            // pairwise tree
            sm[chk] += ((p0 + p1) + (p2 + p3)) + ((p4 + p5) + (p6 + p7));
            union { v4i i4; v8s s8; } up;
            up.i4[0] = pk2(p0, p1);
            up.i4[1] = pk2(p2, p3);
            up.i4[2] = pk2(p4, p5);
            up.i4[3] = pk2(p6, p7);
            const v8s pf = up.s8;

            // NOTE: no s_setprio here (v12 ablation a): near-lockstep waves,
            // priority boost starves SIMD siblings (m190 mechanism).
            #pragma unroll
            for (int nt = 0; nt < 4; ++nt)
                o[chk][nt] = MFMA16(pf, vf[nt], o[chk][nt]);
        }
    }

    // ------- normalize + store: q rows = 32*wave + 16*chk + 4g + r -------
    #pragma unroll
    for (int chk = 0; chk < 2; ++chk) {
        float s = sm[chk];
        s += __shfl_xor(s, 16, 64);
        s += __shfl_xor(s, 32, 64);
        float inv[4];
        #pragma unroll
        for (int r = 0; r < 4; ++r) inv[r] = 1.0f / __shfl(s, 4 * g + r, 64);

        const int rowb = 32 * wave + 16 * chk;
        #pragma unroll
        for (int nt = 0; nt < 4; ++nt)
            #pragma unroll
            for (int r = 0; r < 4; ++r)
                out[obase0 + (size_t)(rowb + 4 * g + r) * CC + h * CH + 16 * nt + m_] =
                    o[chk][nt][r] * inv[r];
    }
}

extern "C" void kernel_launch(void* const* d_in, const int* in_sizes, int n_in,
                              void* d_out, int out_size, void* d_ws, size_t ws_size,
                              hipStream_t stream) {
    (void)in_sizes; (void)n_in; (void)ws_size; (void)out_size;
    const float* x = (const float*)d_in[0];
    const float* W = (const float*)d_in[1];
    const float* b = (const float*)d_in[2];
    float* out = (float*)d_out;
    unsigned short* Wb = (unsigned short*)d_ws;   // 96 KB bf16 W (Q rows pre-scaled)

    wconv_kernel<<<dim3(48), dim3(256), 0, stream>>>(W, Wb);
    lmsa_kernel<<<dim3(2048), dim3(512), 0, stream>>>(x, Wb, b, out);
}

// Round 11
// 152.786 us; speedup vs baseline: 2.1694x; 1.0134x over previous
//
#include <hip/hip_runtime.h>
#include <hip/hip_bf16.h>
#include <cstdint>
#include <cstddef>

// LocalMSA fused v13 == v7 (session-best, 150.5us measured, absmax 0.005859375).
// Final kernel: after 10 rounds, the structure is wedged at ~150us by
// (1) register law: fused per-wave state ~110-130 unified regs -> 4 waves/SIMD
//     (3 spill events prove any cap/explicit-ILP below that cliff regresses);
// (2) LDS law: K[256][64]+Vt[64][256] bf16 = 64KB minimum -> 2 blocks/CU;
// (3) at 42% occupancy the ds_read->QK->exp->pack->PV chain leaves ~55% SIMD
//     idle and every coverage lever crosses cliff (1) or (2).
// Ablations measured: 32x32 MFMA -6%, full-unroll spill -5%, dbuf pipeline
// spill -120%, exp2+tree null, setprio-removal -2%, Q-after-barrier ~0.
// v7 = 16x16x32 MFMA, 64KB LDS, (512,4), c2-outer/chk-inner unroll-2,
// cvt_pk packs everywhere, setprio around PV, Q-proj before barrier.

typedef __attribute__((ext_vector_type(8))) short v8s;
typedef __attribute__((ext_vector_type(4))) float v4f;
typedef __attribute__((ext_vector_type(4))) unsigned short v4u;
typedef __attribute__((ext_vector_type(4))) unsigned int v4i;

#define MFMA16(a, b, c) __builtin_amdgcn_mfma_f32_16x16x32_bf16((a), (b), (c), 0, 0, 0)

constexpr int LL = 256;
constexpr int CC = 128;
constexpr int CH = 64;
constexpr int KS_BYTES = 256 * 128;   // Ks [256 l][64 cc-slot] bf16, 128B rows
constexpr int VT_BYTES = 64 * 512;    // Vt [64 cc][256 l-slot] bf16, 512B rows

__device__ __forceinline__ unsigned short f2bf(float f) {
    union { __hip_bfloat16 b; unsigned short u; } cv;
    cv.b = __float2bfloat16(f);
    return cv.u;
}

// packed pair f32x2 -> bf16x2 (v_cvt_pk_bf16_f32; RNE, == __float2bfloat16)
__device__ __forceinline__ unsigned int pk2(float lo, float hi) {
    union { __hip_bfloat162 b; unsigned int u; } cv;
    cv.b = __float22bfloat162_rn(float2{lo, hi});
    return cv.u;
}

__device__ __forceinline__ v8s load8_f32_bf16(const float* __restrict__ p) {
    float4 a = *reinterpret_cast<const float4*>(p);
    float4 b = *reinterpret_cast<const float4*>(p + 4);
    union { v4i i; v8s s; } u;
    u.i[0] = pk2(a.x, a.y);
    u.i[1] = pk2(a.z, a.w);
    u.i[2] = pk2(b.x, b.y);
    u.i[3] = pk2(b.z, b.w);
    return u.s;
}

__device__ __forceinline__ int swz128(int row, int byte_in_row) {
    return row * 128 + (byte_in_row ^ ((row & 7) << 4));
}
__device__ __forceinline__ int swz512(int row, int byte_in_row) {
    return row * 512 + (byte_in_row ^ ((row & 7) << 4));
}

// W fp32 -> bf16; Q rows (0..127) pre-scaled by 1/sqrt(128)
__global__ __launch_bounds__(256) void wconv_kernel(
    const float* __restrict__ W, unsigned short* __restrict__ Wb)
{
    int i = blockIdx.x * 256 + threadIdx.x;
    float4 v = reinterpret_cast<const float4*>(W)[i];
    const float s = (i < 4096) ? 0.08838834764831845f : 1.0f;
    v4u o;
    o[0] = f2bf(v.x * s); o[1] = f2bf(v.y * s); o[2] = f2bf(v.z * s); o[3] = f2bf(v.w * s);
    reinterpret_cast<v4u*>(Wb)[i] = o;
}

__global__ __launch_bounds__(512, 4) void lmsa_kernel(
    const float* __restrict__ x, const unsigned short* __restrict__ Wb,
    const float* __restrict__ bias, float* __restrict__ out)
{
    __shared__ char smem[KS_BYTES + VT_BYTES];   // 64 KB static
    char* KsB = smem;
    char* VtB = smem + KS_BYTES;

    const int bgh  = blockIdx.x;
    const int bg   = bgh >> 1;
    const int h    = bgh & 1;
    const int tid  = threadIdx.x;
    const int wave = tid >> 6;
    const int lane = tid & 63;
    const int m_   = lane & 15;
    const int g    = lane >> 4;
    const int pm   = 8 * (m_ >> 2) + (m_ & 3);   // within-32 slot base

    const float* xB = x + (size_t)bg * (LL * CC);
    const size_t obase0 = (size_t)bg * (LL * CC);

    const unsigned short* Wq = Wb + (0 * CC + h * CH) * CC;   // pre-scaled
    const unsigned short* Wk = Wb + (1 * CC + h * CH) * CC;
    const unsigned short* Wv = Wb + (2 * CC + h * CH) * CC;
    const float* bq = bias + 0 * CC + h * CH;
    const float* bk = bias + 1 * CC + h * CH;
    const float* bv = bias + 2 * CC + h * CH;

    const float qscale = 0.08838834764831845f;

    // K bias hoist (indexed by col = 16nt+m_)
    float bkr[4];
    #pragma unroll
    for (int nt = 0; nt < 4; ++nt) bkr[nt] = bk[16 * nt + m_];

    // x fragments for this wave's rows [32w, 32w+32)
    v8s af[2][4];
    #pragma unroll
    for (int i = 0; i < 2; ++i)
        #pragma unroll
        for (int ks = 0; ks < 4; ++ks)
            af[i][ks] = load8_f32_bf16(xB + (32 * wave + 16 * i + m_) * CC + 32 * ks + 8 * g);

    // ---- K section: D[l][cc]; row=l=16(2w+i)+4g+r, phys cc=16nt+m_ -> permuted ----
    #pragma unroll 2
    for (int nt = 0; nt < 4; ++nt) {
        v8s bf[4];
        #pragma unroll
        for (int ks = 0; ks < 4; ++ks)
            bf[ks] = *reinterpret_cast<const v8s*>(Wk + (16 * nt + m_) * CC + 32 * ks + 8 * g);
        const int kcol = (32 * (nt >> 1) + 4 * (nt & 1) + pm) << 1;
        #pragma unroll
        for (int i = 0; i < 2; ++i) {
            v4f acc = {0.f, 0.f, 0.f, 0.f};
            #pragma unroll
            for (int ks = 0; ks < 4; ++ks) acc = MFMA16(af[i][ks], bf[ks], acc);
            const int row0 = 16 * (2 * wave + i) + 4 * g;
            const unsigned int d0 = pk2(acc[0] + bkr[nt], acc[1] + bkr[nt]);
            const unsigned int d1 = pk2(acc[2] + bkr[nt], acc[3] + bkr[nt]);
            *(unsigned short*)(KsB + swz128(row0 + 0, kcol)) = (unsigned short)d0;
            *(unsigned short*)(KsB + swz128(row0 + 1, kcol)) = (unsigned short)(d0 >> 16);
            *(unsigned short*)(KsB + swz128(row0 + 2, kcol)) = (unsigned short)d1;
            *(unsigned short*)(KsB + swz128(row0 + 3, kcol)) = (unsigned short)(d1 >> 16);
        }
    }

    // ---- Q^T section: D[cc][q]; row=cc=16mtc+4g+r, col=q=16(2w+i)+m_ ----
    v8s qf[2][2];
    #pragma unroll
    for (int i = 0; i < 2; ++i) {
        v4f qacc[4];
        #pragma unroll
        for (int mtc = 0; mtc < 4; ++mtc) {
            v4f acc = {0.f, 0.f, 0.f, 0.f};
            #pragma unroll
            for (int ks = 0; ks < 4; ++ks) {
                v8s wf = *reinterpret_cast<const v8s*>(Wq + (16 * mtc + m_) * CC + 32 * ks + 8 * g);
                acc = MFMA16(wf, af[i][ks], acc);
            }
            #pragma unroll
            for (int r = 0; r < 4; ++r)
                qacc[mtc][r] = acc[r] + bq[16 * mtc + 4 * g + r] * qscale;  // Wq pre-scaled
        }
        // pack B-frag: slot 8g+j <-> phys cc 32ks+16(j>>2)+4g+(j&3); pairs are
        // (qacc[mtc][0],[1]) and ([2],[3]) -> direct cvt_pk dwords
        #pragma unroll
        for (int ks = 0; ks < 2; ++ks) {
            union { v4i i4; v8s s8; } u;
            u.i4[0] = pk2(qacc[2 * ks][0],     qacc[2 * ks][1]);
            u.i4[1] = pk2(qacc[2 * ks][2],     qacc[2 * ks][3]);
            u.i4[2] = pk2(qacc[2 * ks + 1][0], qacc[2 * ks + 1][1]);
            u.i4[3] = pk2(qacc[2 * ks + 1][2], qacc[2 * ks + 1][3]);
            qf[i][ks] = u.s8;
        }
    }

    // ---- Vt section: D[cc][l]; row=cc=16mtc+4g+r, phys l=16(2w+i)+m_ -> permuted ----
    #pragma unroll 2
    for (int mtc = 0; mtc < 4; ++mtc) {
        v8s wf[4];
        #pragma unroll
        for (int ks = 0; ks < 4; ++ks)
            wf[ks] = *reinterpret_cast<const v8s*>(Wv + (16 * mtc + m_) * CC + 32 * ks + 8 * g);
        v4f bvv = *reinterpret_cast<const v4f*>(bv + 16 * mtc + 4 * g);
        #pragma unroll
        for (int i = 0; i < 2; ++i) {
            const int mt = 2 * wave + i;
            const int vcol = (32 * (mt >> 1) + 4 * (mt & 1) + pm) << 1;
            v4f acc = {0.f, 0.f, 0.f, 0.f};
            #pragma unroll
            for (int ks = 0; ks < 4; ++ks) acc = MFMA16(wf[ks], af[i][ks], acc);
            const int row0 = 16 * mtc + 4 * g;
            const unsigned int d0 = pk2(acc[0] + bvv[0], acc[1] + bvv[1]);
            const unsigned int d1 = pk2(acc[2] + bvv[2], acc[3] + bvv[3]);
            *(unsigned short*)(VtB + swz512(row0 + 0, vcol)) = (unsigned short)d0;
            *(unsigned short*)(VtB + swz512(row0 + 1, vcol)) = (unsigned short)(d0 >> 16);
            *(unsigned short*)(VtB + swz512(row0 + 2, vcol)) = (unsigned short)d1;
            *(unsigned short*)(VtB + swz512(row0 + 3, vcol)) = (unsigned short)(d1 >> 16);
        }
    }

    __syncthreads();

    // ------- attention: c2 OUTER (shared kf/vf reads), chk INNER (2 chains) ---
    v4f o[2][4];
    #pragma unroll
    for (int chk = 0; chk < 2; ++chk)
        #pragma unroll
        for (int nt = 0; nt < 4; ++nt) o[chk][nt] = v4f{0.f, 0.f, 0.f, 0.f};
    float sm[2] = {0.f, 0.f};

    #pragma unroll 2
    for (int c2 = 0; c2 < 8; ++c2) {       // 8 key-chunks of 32
        // shared LDS reads for this chunk (used by BOTH chk chains)
        v8s kf0[2], kf1[2], vf[4];
        #pragma unroll
        for (int ks = 0; ks < 2; ++ks)
            kf0[ks] = *reinterpret_cast<const v8s*>(
                KsB + swz128(32 * c2 + m_, (32 * ks + 8 * g) << 1));
        #pragma unroll
        for (int ks = 0; ks < 2; ++ks)
            kf1[ks] = *reinterpret_cast<const v8s*>(
                KsB + swz128(32 * c2 + 16 + m_, (32 * ks + 8 * g) << 1));
        #pragma unroll
        for (int nt = 0; nt < 4; ++nt)
            vf[nt] = *reinterpret_cast<const v8s*>(
                VtB + swz512(16 * nt + m_, 64 * c2 + 16 * g));

        #pragma unroll
        for (int chk = 0; chk < 2; ++chk) {
            v4f s0 = {0.f, 0.f, 0.f, 0.f}, s1 = {0.f, 0.f, 0.f, 0.f};
            #pragma unroll
            for (int ks = 0; ks < 2; ++ks) s0 = MFMA16(kf0[ks], qf[chk][ks], s0);
            #pragma unroll
            for (int ks = 0; ks < 2; ++ks) s1 = MFMA16(kf1[ks], qf[chk][ks], s1);

            // lane(m_,g): P[q=m_][k=32c2+16t+4g+r]; A-frag slot 8g+j: t=j>>2, r=j&3
            const float p0 = __expf(s0[0]), p1 = __expf(s0[1]);
            const float p2 = __expf(s0[2]), p3 = __expf(s0[3]);
            const float p4 = __expf(s1[0]), p5 = __expf(s1[1]);
            const float p6 = __expf(s1[2]), p7 = __expf(s1[3]);
            // keep EXACT v6 accumulation order for sm (bit-identical denom)
            sm[chk] += p0; sm[chk] += p1; sm[chk] += p2; sm[chk] += p3;
            sm[chk] += p4; sm[chk] += p5; sm[chk] += p6; sm[chk] += p7;
            union { v4i i4; v8s s8; } up;
            up.i4[0] = pk2(p0, p1);
            up.i4[1] = pk2(p2, p3);
            up.i4[2] = pk2(p4, p5);
            up.i4[3] = pk2(p6, p7);
            const v8s pf = up.s8;

            __builtin_amdgcn_s_setprio(1);
            #pragma unroll
            for (int nt = 0; nt < 4; ++nt)
                o[chk][nt] = MFMA16(pf, vf[nt], o[chk][nt]);
            __builtin_amdgcn_s_setprio(0);
        }
    }

    // ------- normalize + store: q rows = 32*wave + 16*chk + 4g + r -------
    #pragma unroll
    for (int chk = 0; chk < 2; ++chk) {
        float s = sm[chk];
        s += __shfl_xor(s, 16, 64);
        s += __shfl_xor(s, 32, 64);
        float inv[4];
        #pragma unroll
        for (int r = 0; r < 4; ++r) inv[r] = 1.0f / __shfl(s, 4 * g + r, 64);

        const int rowb = 32 * wave + 16 * chk;
        #pragma unroll
        for (int nt = 0; nt < 4; ++nt)
            #pragma unroll
            for (int r = 0; r < 4; ++r)
                out[obase0 + (size_t)(rowb + 4 * g + r) * CC + h * CH + 16 * nt + m_] =
                    o[chk][nt][r] * inv[r];
    }
}

extern "C" void kernel_launch(void* const* d_in, const int* in_sizes, int n_in,
                              void* d_out, int out_size, void* d_ws, size_t ws_size,
                              hipStream_t stream) {
    (void)in_sizes; (void)n_in; (void)ws_size; (void)out_size;
    const float* x = (const float*)d_in[0];
    const float* W = (const float*)d_in[1];
    const float* b = (const float*)d_in[2];
    float* out = (float*)d_out;
    unsigned short* Wb = (unsigned short*)d_ws;   // 96 KB bf16 W (Q rows pre-scaled)

    wconv_kernel<<<dim3(48), dim3(256), 0, stream>>>(W, Wb);
    lmsa_kernel<<<dim3(2048), dim3(512), 0, stream>>>(x, Wb, b, out);
}

// Round 12
// 148.857 us; speedup vs baseline: 2.2266x; 1.0264x over previous
//
#include <hip/hip_runtime.h>
#include <hip/hip_bf16.h>
#include <cstdint>
#include <cstddef>

// LocalMSA fused v14: v13/v7 base (session best, 150.5-152.8us, absmax
// 0.005859375) + ONE low-risk ILP change in the attention inner window:
// both chk chains' QK^T MFMAs issue FIRST (8 independent MFMAs, two acc
// sets, +8 regs), then chk0's exp->pack->PV, then chk1's. chk0's exp
// latency hides under chk1's QK; chk1's exp hides under chk0's PV.
// Per-value op order and per-chk sm order unchanged -> absmax must stay
// exactly 0.005859375. Register delta +8 (~80 total) - far from the 128
// cliff (unlike v9b/v11 which spilled).
// Sentinels: steady WRITE_SIZE ~131-148K KB (no spill; jump => revert),
// VGPR ~64-72 arch, LDS 65536, occupancy ~42%, bank conflict ~2.1M.
// If null (152+-2): scheduler already interleaved; plateau confirmed.

typedef __attribute__((ext_vector_type(8))) short v8s;
typedef __attribute__((ext_vector_type(4))) float v4f;
typedef __attribute__((ext_vector_type(4))) unsigned short v4u;
typedef __attribute__((ext_vector_type(4))) unsigned int v4i;

#define MFMA16(a, b, c) __builtin_amdgcn_mfma_f32_16x16x32_bf16((a), (b), (c), 0, 0, 0)

constexpr int LL = 256;
constexpr int CC = 128;
constexpr int CH = 64;
constexpr int KS_BYTES = 256 * 128;   // Ks [256 l][64 cc-slot] bf16, 128B rows
constexpr int VT_BYTES = 64 * 512;    // Vt [64 cc][256 l-slot] bf16, 512B rows

__device__ __forceinline__ unsigned short f2bf(float f) {
    union { __hip_bfloat16 b; unsigned short u; } cv;
    cv.b = __float2bfloat16(f);
    return cv.u;
}

// packed pair f32x2 -> bf16x2 (v_cvt_pk_bf16_f32; RNE, == __float2bfloat16)
__device__ __forceinline__ unsigned int pk2(float lo, float hi) {
    union { __hip_bfloat162 b; unsigned int u; } cv;
    cv.b = __float22bfloat162_rn(float2{lo, hi});
    return cv.u;
}

__device__ __forceinline__ v8s load8_f32_bf16(const float* __restrict__ p) {
    float4 a = *reinterpret_cast<const float4*>(p);
    float4 b = *reinterpret_cast<const float4*>(p + 4);
    union { v4i i; v8s s; } u;
    u.i[0] = pk2(a.x, a.y);
    u.i[1] = pk2(a.z, a.w);
    u.i[2] = pk2(b.x, b.y);
    u.i[3] = pk2(b.z, b.w);
    return u.s;
}

__device__ __forceinline__ int swz128(int row, int byte_in_row) {
    return row * 128 + (byte_in_row ^ ((row & 7) << 4));
}
__device__ __forceinline__ int swz512(int row, int byte_in_row) {
    return row * 512 + (byte_in_row ^ ((row & 7) << 4));
}

// W fp32 -> bf16; Q rows (0..127) pre-scaled by 1/sqrt(128)
__global__ __launch_bounds__(256) void wconv_kernel(
    const float* __restrict__ W, unsigned short* __restrict__ Wb)
{
    int i = blockIdx.x * 256 + threadIdx.x;
    float4 v = reinterpret_cast<const float4*>(W)[i];
    const float s = (i < 4096) ? 0.08838834764831845f : 1.0f;
    v4u o;
    o[0] = f2bf(v.x * s); o[1] = f2bf(v.y * s); o[2] = f2bf(v.z * s); o[3] = f2bf(v.w * s);
    reinterpret_cast<v4u*>(Wb)[i] = o;
}

__global__ __launch_bounds__(512, 4) void lmsa_kernel(
    const float* __restrict__ x, const unsigned short* __restrict__ Wb,
    const float* __restrict__ bias, float* __restrict__ out)
{
    __shared__ char smem[KS_BYTES + VT_BYTES];   // 64 KB static
    char* KsB = smem;
    char* VtB = smem + KS_BYTES;

    const int bgh  = blockIdx.x;
    const int bg   = bgh >> 1;
    const int h    = bgh & 1;
    const int tid  = threadIdx.x;
    const int wave = tid >> 6;
    const int lane = tid & 63;
    const int m_   = lane & 15;
    const int g    = lane >> 4;
    const int pm   = 8 * (m_ >> 2) + (m_ & 3);   // within-32 slot base

    const float* xB = x + (size_t)bg * (LL * CC);
    const size_t obase0 = (size_t)bg * (LL * CC);

    const unsigned short* Wq = Wb + (0 * CC + h * CH) * CC;   // pre-scaled
    const unsigned short* Wk = Wb + (1 * CC + h * CH) * CC;
    const unsigned short* Wv = Wb + (2 * CC + h * CH) * CC;
    const float* bq = bias + 0 * CC + h * CH;
    const float* bk = bias + 1 * CC + h * CH;
    const float* bv = bias + 2 * CC + h * CH;

    const float qscale = 0.08838834764831845f;

    // K bias hoist (indexed by col = 16nt+m_)
    float bkr[4];
    #pragma unroll
    for (int nt = 0; nt < 4; ++nt) bkr[nt] = bk[16 * nt + m_];

    // x fragments for this wave's rows [32w, 32w+32)
    v8s af[2][4];
    #pragma unroll
    for (int i = 0; i < 2; ++i)
        #pragma unroll
        for (int ks = 0; ks < 4; ++ks)
            af[i][ks] = load8_f32_bf16(xB + (32 * wave + 16 * i + m_) * CC + 32 * ks + 8 * g);

    // ---- K section: D[l][cc]; row=l=16(2w+i)+4g+r, phys cc=16nt+m_ -> permuted ----
    #pragma unroll 2
    for (int nt = 0; nt < 4; ++nt) {
        v8s bf[4];
        #pragma unroll
        for (int ks = 0; ks < 4; ++ks)
            bf[ks] = *reinterpret_cast<const v8s*>(Wk + (16 * nt + m_) * CC + 32 * ks + 8 * g);
        const int kcol = (32 * (nt >> 1) + 4 * (nt & 1) + pm) << 1;
        #pragma unroll
        for (int i = 0; i < 2; ++i) {
            v4f acc = {0.f, 0.f, 0.f, 0.f};
            #pragma unroll
            for (int ks = 0; ks < 4; ++ks) acc = MFMA16(af[i][ks], bf[ks], acc);
            const int row0 = 16 * (2 * wave + i) + 4 * g;
            const unsigned int d0 = pk2(acc[0] + bkr[nt], acc[1] + bkr[nt]);
            const unsigned int d1 = pk2(acc[2] + bkr[nt], acc[3] + bkr[nt]);
            *(unsigned short*)(KsB + swz128(row0 + 0, kcol)) = (unsigned short)d0;
            *(unsigned short*)(KsB + swz128(row0 + 1, kcol)) = (unsigned short)(d0 >> 16);
            *(unsigned short*)(KsB + swz128(row0 + 2, kcol)) = (unsigned short)d1;
            *(unsigned short*)(KsB + swz128(row0 + 3, kcol)) = (unsigned short)(d1 >> 16);
        }
    }

    // ---- Q^T section: D[cc][q]; row=cc=16mtc+4g+r, col=q=16(2w+i)+m_ ----
    v8s qf[2][2];
    #pragma unroll
    for (int i = 0; i < 2; ++i) {
        v4f qacc[4];
        #pragma unroll
        for (int mtc = 0; mtc < 4; ++mtc) {
            v4f acc = {0.f, 0.f, 0.f, 0.f};
            #pragma unroll
            for (int ks = 0; ks < 4; ++ks) {
                v8s wf = *reinterpret_cast<const v8s*>(Wq + (16 * mtc + m_) * CC + 32 * ks + 8 * g);
                acc = MFMA16(wf, af[i][ks], acc);
            }
            #pragma unroll
            for (int r = 0; r < 4; ++r)
                qacc[mtc][r] = acc[r] + bq[16 * mtc + 4 * g + r] * qscale;  // Wq pre-scaled
        }
        // pack B-frag: slot 8g+j <-> phys cc 32ks+16(j>>2)+4g+(j&3); pairs are
        // (qacc[mtc][0],[1]) and ([2],[3]) -> direct cvt_pk dwords
        #pragma unroll
        for (int ks = 0; ks < 2; ++ks) {
            union { v4i i4; v8s s8; } u;
            u.i4[0] = pk2(qacc[2 * ks][0],     qacc[2 * ks][1]);
            u.i4[1] = pk2(qacc[2 * ks][2],     qacc[2 * ks][3]);
            u.i4[2] = pk2(qacc[2 * ks + 1][0], qacc[2 * ks + 1][1]);
            u.i4[3] = pk2(qacc[2 * ks + 1][2], qacc[2 * ks + 1][3]);
            qf[i][ks] = u.s8;
        }
    }

    // ---- Vt section: D[cc][l]; row=cc=16mtc+4g+r, phys l=16(2w+i)+m_ -> permuted ----
    #pragma unroll 2
    for (int mtc = 0; mtc < 4; ++mtc) {
        v8s wf[4];
        #pragma unroll
        for (int ks = 0; ks < 4; ++ks)
            wf[ks] = *reinterpret_cast<const v8s*>(Wv + (16 * mtc + m_) * CC + 32 * ks + 8 * g);
        v4f bvv = *reinterpret_cast<const v4f*>(bv + 16 * mtc + 4 * g);
        #pragma unroll
        for (int i = 0; i < 2; ++i) {
            const int mt = 2 * wave + i;
            const int vcol = (32 * (mt >> 1) + 4 * (mt & 1) + pm) << 1;
            v4f acc = {0.f, 0.f, 0.f, 0.f};
            #pragma unroll
            for (int ks = 0; ks < 4; ++ks) acc = MFMA16(wf[ks], af[i][ks], acc);
            const int row0 = 16 * mtc + 4 * g;
            const unsigned int d0 = pk2(acc[0] + bvv[0], acc[1] + bvv[1]);
            const unsigned int d1 = pk2(acc[2] + bvv[2], acc[3] + bvv[3]);
            *(unsigned short*)(VtB + swz512(row0 + 0, vcol)) = (unsigned short)d0;
            *(unsigned short*)(VtB + swz512(row0 + 1, vcol)) = (unsigned short)(d0 >> 16);
            *(unsigned short*)(VtB + swz512(row0 + 2, vcol)) = (unsigned short)d1;
            *(unsigned short*)(VtB + swz512(row0 + 3, vcol)) = (unsigned short)(d1 >> 16);
        }
    }

    __syncthreads();

    // ------- attention: c2 outer; BOTH chk chains' QK issue first, then
    //         per-chk exp->pack->PV (chk0's exp hides under chk1's QK) -------
    v4f o[2][4];
    #pragma unroll
    for (int chk = 0; chk < 2; ++chk)
        #pragma unroll
        for (int nt = 0; nt < 4; ++nt) o[chk][nt] = v4f{0.f, 0.f, 0.f, 0.f};
    float sm[2] = {0.f, 0.f};

    #pragma unroll 2
    for (int c2 = 0; c2 < 8; ++c2) {       // 8 key-chunks of 32
        // shared LDS reads for this chunk (used by BOTH chk chains)
        v8s kf0[2], kf1[2], vf[4];
        #pragma unroll
        for (int ks = 0; ks < 2; ++ks)
            kf0[ks] = *reinterpret_cast<const v8s*>(
                KsB + swz128(32 * c2 + m_, (32 * ks + 8 * g) << 1));
        #pragma unroll
        for (int ks = 0; ks < 2; ++ks)
            kf1[ks] = *reinterpret_cast<const v8s*>(
                KsB + swz128(32 * c2 + 16 + m_, (32 * ks + 8 * g) << 1));
        #pragma unroll
        for (int nt = 0; nt < 4; ++nt)
            vf[nt] = *reinterpret_cast<const v8s*>(
                VtB + swz512(16 * nt + m_, 64 * c2 + 16 * g));

        // phase 1: QK^T for BOTH chains (8 independent MFMAs back-to-back)
        v4f s0[2], s1[2];
        #pragma unroll
        for (int chk = 0; chk < 2; ++chk) {
            s0[chk] = v4f{0.f, 0.f, 0.f, 0.f};
            s1[chk] = v4f{0.f, 0.f, 0.f, 0.f};
            #pragma unroll
            for (int ks = 0; ks < 2; ++ks) s0[chk] = MFMA16(kf0[ks], qf[chk][ks], s0[chk]);
            #pragma unroll
            for (int ks = 0; ks < 2; ++ks) s1[chk] = MFMA16(kf1[ks], qf[chk][ks], s1[chk]);
        }

        // phase 2: per-chk exp -> pack -> PV (chk0 finish overlaps chk1 QK tail)
        #pragma unroll
        for (int chk = 0; chk < 2; ++chk) {
            // lane(m_,g): P[q=m_][k=32c2+16t+4g+r]; A-frag slot 8g+j: t=j>>2, r=j&3
            const float p0 = __expf(s0[chk][0]), p1 = __expf(s0[chk][1]);
            const float p2 = __expf(s0[chk][2]), p3 = __expf(s0[chk][3]);
            const float p4 = __expf(s1[chk][0]), p5 = __expf(s1[chk][1]);
            const float p6 = __expf(s1[chk][2]), p7 = __expf(s1[chk][3]);
            // keep EXACT v6/v7 accumulation order for sm (bit-identical denom)
            sm[chk] += p0; sm[chk] += p1; sm[chk] += p2; sm[chk] += p3;
            sm[chk] += p4; sm[chk] += p5; sm[chk] += p6; sm[chk] += p7;
            union { v4i i4; v8s s8; } up;
            up.i4[0] = pk2(p0, p1);
            up.i4[1] = pk2(p2, p3);
            up.i4[2] = pk2(p4, p5);
            up.i4[3] = pk2(p6, p7);
            const v8s pf = up.s8;

            __builtin_amdgcn_s_setprio(1);
            #pragma unroll
            for (int nt = 0; nt < 4; ++nt)
                o[chk][nt] = MFMA16(pf, vf[nt], o[chk][nt]);
            __builtin_amdgcn_s_setprio(0);
        }
    }

    // ------- normalize + store: q rows = 32*wave + 16*chk + 4g + r -------
    #pragma unroll
    for (int chk = 0; chk < 2; ++chk) {
        float s = sm[chk];
        s += __shfl_xor(s, 16, 64);
        s += __shfl_xor(s, 32, 64);
        float inv[4];
        #pragma unroll
        for (int r = 0; r < 4; ++r) inv[r] = 1.0f / __shfl(s, 4 * g + r, 64);

        const int rowb = 32 * wave + 16 * chk;
        #pragma unroll
        for (int nt = 0; nt < 4; ++nt)
            #pragma unroll
            for (int r = 0; r < 4; ++r)
                out[obase0 + (size_t)(rowb + 4 * g + r) * CC + h * CH + 16 * nt + m_] =
                    o[chk][nt][r] * inv[r];
    }
}

extern "C" void kernel_launch(void* const* d_in, const int* in_sizes, int n_in,
                              void* d_out, int out_size, void* d_ws, size_t ws_size,
                              hipStream_t stream) {
    (void)in_sizes; (void)n_in; (void)ws_size; (void)out_size;
    const float* x = (const float*)d_in[0];
    const float* W = (const float*)d_in[1];
    const float* b = (const float*)d_in[2];
    float* out = (float*)d_out;
    unsigned short* Wb = (unsigned short*)d_ws;   // 96 KB bf16 W (Q rows pre-scaled)

    wconv_kernel<<<dim3(48), dim3(256), 0, stream>>>(W, Wb);
    lmsa_kernel<<<dim3(2048), dim3(512), 0, stream>>>(x, Wb, b, out);
}